// Round 9
// baseline (2172.779 us; speedup 1.0000x reference)
//
#include <hip/hip_runtime.h>
#include <hip/hip_fp16.h>
#include <cstdint>
#include <cstddef>

// ---------------------------------------------------------------------------
// GCN: 3x GraphConv(norm='both') + linear head, fp32 in/out.
// Round 9:
//  - agg restructured: one block per 128-dst range, f32 LDS accumulators
//    (stride 65 = bank-conflict-free), waves stream the bucket segment
//    (packed (src<<7)|dstlow) and ds_add_f32 gathered rows; in-degree counted
//    in-pass -> csr_kernel / rptr / degi / esrc all deleted.
//  - CSR build stops at bucket stage; dego histogram for invo unchanged.
//  - MFMA GEMMs unchanged.
// ---------------------------------------------------------------------------

#define WG 256
static constexpr int NCHUNK = 512;   // edge chunks for dst bucketing
static constexpr int RW_SH  = 7;     // range width = 128 nodes (dst>>7)
static constexpr int RWID   = 1 << RW_SH;
static constexpr int BPRO   = 6256;  // bins per range for dego histogram (25KB)
static constexpr int NRO    = 16;    // dego ranges (16*6256 >= 100000)
static constexpr int NCO    = 40;    // edge chunks for dego histogram

typedef _Float16 half8 __attribute__((ext_vector_type(8)));
typedef float f32x4 __attribute__((ext_vector_type(4)));

__device__ __forceinline__ int block_scan_excl(int v, int tid, int* sd, int& total) {
  sd[tid] = v;
  __syncthreads();
  for (int off = 1; off < 256; off <<= 1) {
    int t = (tid >= off) ? sd[tid - off] : 0;
    __syncthreads();
    sd[tid] += t;
    __syncthreads();
  }
  int incl = sd[tid];
  total = sd[255];
  __syncthreads();
  return incl - v;
}

// --- Pass A: per-chunk coarse histogram over dst ranges ---------------------
__global__ __launch_bounds__(WG) void coarse_hist_kernel(const int* __restrict__ dst,
                                                         int* __restrict__ cntA,
                                                         int NR, int E, int EPC) {
  __shared__ int cnt[1024];
  const int c = blockIdx.x, tid = threadIdx.x;
  for (int i = tid; i < NR; i += WG) cnt[i] = 0;
  __syncthreads();
  const int base = c * EPC;
  const int nv4 = EPC >> 2;
  const int4* d4 = (const int4*)(dst + base);
  for (int i = tid; i < nv4; i += WG) {
    const int e = base + (i << 2);
    if (e + 3 < E) {
      const int4 v = d4[i];
      atomicAdd(&cnt[v.x >> RW_SH], 1);
      atomicAdd(&cnt[v.y >> RW_SH], 1);
      atomicAdd(&cnt[v.z >> RW_SH], 1);
      atomicAdd(&cnt[v.w >> RW_SH], 1);
    } else {
      for (int j = 0; j < 4; ++j) {
        const int ee = e + j;
        if (ee < E) atomicAdd(&cnt[dst[ee] >> RW_SH], 1);
      }
    }
  }
  __syncthreads();
  for (int i = tid; i < NR; i += WG) cntA[i * NCHUNK + c] = cnt[i];
}

// --- Pass B1: per-range exclusive scan over the 512 chunks ------------------
__global__ __launch_bounds__(WG) void chunkscan_kernel(const int* __restrict__ cntA,
                                                       int* __restrict__ base_rel,
                                                       int* __restrict__ cntR) {
  __shared__ int sd[256];
  const int r = blockIdx.x, tid = threadIdx.x;
  const int row = r * NCHUNK;
  int t0, t1;
  const int v0 = cntA[row + tid];
  const int e0 = block_scan_excl(v0, tid, sd, t0);
  base_rel[row + tid] = e0;
  const int v1 = cntA[row + 256 + tid];
  const int e1 = block_scan_excl(v1, tid, sd, t1);
  base_rel[row + 256 + tid] = t0 + e1;
  if (tid == 0) cntR[r] = t0 + t1;
}

// --- Pass B2: exclusive scan over up to 1024 ranges -> rangeStart -----------
__global__ __launch_bounds__(WG) void rangescan_kernel(const int* __restrict__ cntR,
                                                       int* __restrict__ rangeStart,
                                                       int NR, int E) {
  __shared__ int sd[256];
  const int tid = threadIdx.x;
  int carry = 0;
  for (int base = 0; base < NR; base += 256) {
    const int idx = base + tid;
    const int v = (idx < NR) ? cntR[idx] : 0;
    int tot;
    const int e = block_scan_excl(v, tid, sd, tot);
    if (idx < NR) rangeStart[idx] = carry + e;
    carry += tot;
  }
  if (tid == 0) rangeStart[NR] = E;
}

// --- Pass C: bucket scatter with LDS cursors, 4B packed entries -------------
// entry = (src << RW_SH) | (dst & (RWID-1)); src < 2^17, RW_SH=7 -> 24 bits
__global__ __launch_bounds__(WG) void bucket_kernel(const int* __restrict__ src,
                                                    const int* __restrict__ dst,
                                                    const int* __restrict__ base_rel,
                                                    const int* __restrict__ rangeStart,
                                                    int* __restrict__ bucket,
                                                    int NR, int E, int EPC) {
  __shared__ int cur[1024];
  const int c = blockIdx.x, tid = threadIdx.x;
  for (int i = tid; i < NR; i += WG) cur[i] = rangeStart[i] + base_rel[i * NCHUNK + c];
  __syncthreads();
  const int base = c * EPC;
  const int nv4 = EPC >> 2;
  const int4* s4 = (const int4*)(src + base);
  const int4* d4 = (const int4*)(dst + base);
  for (int i = tid; i < nv4; i += WG) {
    const int e = base + (i << 2);
    if (e + 3 < E) {
      const int4 sv = s4[i];
      const int4 dv = d4[i];
      int p;
      p = atomicAdd(&cur[dv.x >> RW_SH], 1); bucket[p] = (sv.x << RW_SH) | (dv.x & (RWID - 1));
      p = atomicAdd(&cur[dv.y >> RW_SH], 1); bucket[p] = (sv.y << RW_SH) | (dv.y & (RWID - 1));
      p = atomicAdd(&cur[dv.z >> RW_SH], 1); bucket[p] = (sv.z << RW_SH) | (dv.z & (RWID - 1));
      p = atomicAdd(&cur[dv.w >> RW_SH], 1); bucket[p] = (sv.w << RW_SH) | (dv.w & (RWID - 1));
    } else {
      for (int j = 0; j < 4; ++j) {
        const int ee = e + j;
        if (ee < E) {
          const int s = src[ee], d = dst[ee];
          const int p = atomicAdd(&cur[d >> RW_SH], 1);
          bucket[p] = (s << RW_SH) | (d & (RWID - 1));
        }
      }
    }
  }
}

// --- dego: privatized LDS histogram over src, slab + reduce + invo ----------
__global__ __launch_bounds__(WG) void dego_hist_kernel(const int* __restrict__ src,
                                                       int* __restrict__ slab,
                                                       int N, int E, int EPCO) {
  __shared__ int h[BPRO];  // 25 KB
  const int rr = blockIdx.x / NCO, cc = blockIdx.x % NCO;
  const int tid = threadIdx.x;
  for (int i = tid; i < (BPRO >> 2); i += WG) ((int4*)h)[i] = make_int4(0, 0, 0, 0);
  __syncthreads();
  const int lo = rr * BPRO;
  const int base = cc * EPCO;
  const int nv4 = EPCO >> 2;
  const int4* s4 = (const int4*)(src + base);
  for (int i = tid; i < nv4; i += WG) {
    const int e = base + (i << 2);
    if (e + 3 < E) {
      const int4 v = s4[i];
      unsigned b;
      b = (unsigned)(v.x - lo); if (b < (unsigned)BPRO) atomicAdd(&h[b], 1);
      b = (unsigned)(v.y - lo); if (b < (unsigned)BPRO) atomicAdd(&h[b], 1);
      b = (unsigned)(v.z - lo); if (b < (unsigned)BPRO) atomicAdd(&h[b], 1);
      b = (unsigned)(v.w - lo); if (b < (unsigned)BPRO) atomicAdd(&h[b], 1);
    } else {
      for (int j = 0; j < 4; ++j) {
        const int ee = e + j;
        if (ee < E) {
          const unsigned b = (unsigned)(src[ee] - lo);
          if (b < (unsigned)BPRO) atomicAdd(&h[b], 1);
        }
      }
    }
  }
  __syncthreads();
  int* srow = slab + (size_t)cc * N;
  for (int i = tid; i < (BPRO >> 2); i += WG) {
    const int g = lo + (i << 2);
    if (g + 3 < N) {
      ((int4*)(srow + g))[0] = ((const int4*)h)[i];
    } else {
      for (int j = 0; j < 4; ++j)
        if (g + j < N) srow[g + j] = h[(i << 2) + j];
    }
  }
}

__global__ __launch_bounds__(WG) void dego_reduce_invo_kernel(const int* __restrict__ slab,
                                                              float* __restrict__ invo, int N) {
  const int i = blockIdx.x * WG + threadIdx.x;
  if (i >= N) return;
  int s = 0;
#pragma unroll
  for (int c = 0; c < NCO; ++c) s += slab[(size_t)c * N + i];
  if (s < 1) s = 1;
  invo[i] = rsqrtf((float)s);
}

// --- weight transpose+convert: WT[c][k] = (f16)W[k][c] ----------------------
__global__ __launch_bounds__(WG) void wtrans_kernel(const float* __restrict__ W0,
                                                    const float* __restrict__ W1,
                                                    const float* __restrict__ W2,
                                                    const float* __restrict__ Wl,
                                                    _Float16* __restrict__ T0,
                                                    _Float16* __restrict__ T1,
                                                    _Float16* __restrict__ T2,
                                                    _Float16* __restrict__ Tl) {
  const float* W; _Float16* T; int K;
  switch (blockIdx.x) {
    case 0: W = W0; T = T0; K = 128; break;
    case 1: W = W1; T = T1; K = 64; break;
    case 2: W = W2; T = T2; K = 64; break;
    default: W = Wl; T = Tl; K = 64; break;
  }
  for (int i = threadIdx.x; i < K * 64; i += WG) {
    const int k = i >> 6, c = i & 63;
    T[c * K + k] = (_Float16)W[i];
  }
}

// --- MFMA conv GEMM: hP[r][c] = f16( invo[r] * sum_k in[r][k] W[k][c] ) -----
template <int K, bool F16IN>
__global__ __launch_bounds__(256) void gemm_conv_mfma(const void* __restrict__ inv_,
                                                      const _Float16* __restrict__ WT,
                                                      const float* __restrict__ invo,
                                                      _Float16* __restrict__ hP, int N) {
  const int tid = threadIdx.x;
  const int w = tid >> 6, l = tid & 63;
  const int rowA = blockIdx.x * 64 + w * 16 + (l & 15);
  const int ar = (rowA < N) ? rowA : (N - 1);
  const int g8 = (l >> 4) * 8;

  f32x4 acc[4];
#pragma unroll
  for (int t = 0; t < 4; ++t) acc[t] = (f32x4){0.f, 0.f, 0.f, 0.f};

#pragma unroll
  for (int s = 0; s < K / 32; ++s) {
    const int kb = s * 32 + g8;
    half8 a;
    if constexpr (F16IN) {
      a = *(const half8*)((const _Float16*)inv_ + (size_t)ar * K + kb);
    } else {
      const float* in = (const float*)inv_;
      const float4 f0 = *(const float4*)(in + (size_t)ar * K + kb);
      const float4 f1 = *(const float4*)(in + (size_t)ar * K + kb + 4);
      a[0] = (_Float16)f0.x; a[1] = (_Float16)f0.y; a[2] = (_Float16)f0.z; a[3] = (_Float16)f0.w;
      a[4] = (_Float16)f1.x; a[5] = (_Float16)f1.y; a[6] = (_Float16)f1.z; a[7] = (_Float16)f1.w;
    }
#pragma unroll
    for (int t = 0; t < 4; ++t) {
      const half8 b = *(const half8*)(WT + (size_t)(16 * t + (l & 15)) * K + kb);
      acc[t] = __builtin_amdgcn_mfma_f32_16x16x32_f16(a, b, acc[t], 0, 0, 0);
    }
  }

  const int rbase = blockIdx.x * 64 + w * 16 + (l >> 4) * 4;
#pragma unroll
  for (int r = 0; r < 4; ++r) {
    const int row = rbase + r;
    if (row < N) {
      const float sc = invo[row];
#pragma unroll
      for (int t = 0; t < 4; ++t)
        hP[(size_t)row * 64 + 16 * t + (l & 15)] = (_Float16)(acc[t][r] * sc);
    }
  }
}

// --- MFMA head GEMM (f16 in): out[r][c] = sum_k in[r][k] W[k][c] + bias[c] --
__global__ __launch_bounds__(256) void gemm_head_mfma(const _Float16* __restrict__ in,
                                                      const _Float16* __restrict__ WT,
                                                      const float* __restrict__ bias,
                                                      float* __restrict__ out, int N) {
  constexpr int K = 64;
  const int tid = threadIdx.x;
  const int w = tid >> 6, l = tid & 63;
  const int rowA = blockIdx.x * 64 + w * 16 + (l & 15);
  const int ar = (rowA < N) ? rowA : (N - 1);
  const int g8 = (l >> 4) * 8;

  f32x4 acc[4];
#pragma unroll
  for (int t = 0; t < 4; ++t) acc[t] = (f32x4){0.f, 0.f, 0.f, 0.f};

#pragma unroll
  for (int s = 0; s < K / 32; ++s) {
    const int kb = s * 32 + g8;
    const half8 a = *(const half8*)(in + (size_t)ar * K + kb);
#pragma unroll
    for (int t = 0; t < 4; ++t) {
      const half8 b = *(const half8*)(WT + (size_t)(16 * t + (l & 15)) * K + kb);
      acc[t] = __builtin_amdgcn_mfma_f32_16x16x32_f16(a, b, acc[t], 0, 0, 0);
    }
  }

  const int rbase = blockIdx.x * 64 + w * 16 + (l >> 4) * 4;
#pragma unroll
  for (int r = 0; r < 4; ++r) {
    const int row = rbase + r;
    if (row < N) {
#pragma unroll
      for (int t = 0; t < 4; ++t) {
        const int c = 16 * t + (l & 15);
        out[(size_t)row * 64 + c] = acc[t][r] + bias[c];
      }
    }
  }
}

// --- edge-parallel range aggregation ----------------------------------------
// Block = one 128-dst range. acc[128][65] f32 in LDS (stride 65: bank =
// (n + j) & 31, conflict-free). Waves stream bucket[s0..s1): 8 edges per
// wave-group, lane (g,f8) gathers hp[src*64 + f8*8..+8] (b128) and ds_add_f32
// into acc[dstlow]. In-degree counted in-pass; epilogue applies
// rsqrt(max(cnt,1)), bias, optional ELU, writes f16.
__global__ __launch_bounds__(256) void agg_range_kernel(const _Float16* __restrict__ hp,
                                                        const int* __restrict__ bucket,
                                                        const int* __restrict__ rangeStart,
                                                        const float* __restrict__ bias,
                                                        _Float16* __restrict__ out, int N,
                                                        int apply_elu) {
  __shared__ float acc[RWID * 65];
  __shared__ int cnti[RWID];
  const int r = blockIdx.x, tid = threadIdx.x;

  for (int i = tid; i < (RWID * 65) / 4; i += WG)
    ((f32x4*)acc)[i] = (f32x4){0.f, 0.f, 0.f, 0.f};
  if (tid < RWID) cnti[tid] = 0;
  __syncthreads();

  const int s0 = rangeStart[r], s1 = rangeStart[r + 1];
  const int L = s1 - s0;
  const int lane = tid & 63, wv = tid >> 6;
  const int g = lane >> 3, f8 = lane & 7;

  for (int base = wv * 8; base < L; base += 32) {   // 4 waves x 8 edges
    const int idx = base + g;
    if (idx < L) {
      const int pk = bucket[s0 + idx];
      const int dl = pk & (RWID - 1);
      const int sr = pk >> RW_SH;
      const half8 hv = *(const half8*)(hp + (size_t)sr * 64 + f8 * 8);
      float* arow = acc + dl * 65 + f8 * 8;
#pragma unroll
      for (int k = 0; k < 8; ++k) atomicAdd(&arow[k], (float)hv[k]);
      if (f8 == 0) atomicAdd(&cnti[dl], 1);
    }
  }
  __syncthreads();

  // epilogue: thread -> (node = tid>>1, half = tid&1 -> 32 features)
  const int n = tid >> 1;
  const int node = (r << RW_SH) + n;
  if (node < N) {
    const int c0 = (tid & 1) * 32;
    int dc = cnti[n]; if (dc < 1) dc = 1;
    const float vi = rsqrtf((float)dc);
#pragma unroll
    for (int o = 0; o < 4; ++o) {
      half8 ov;
#pragma unroll
      for (int k = 0; k < 8; ++k) {
        const int c = c0 + o * 8 + k;
        float v = acc[n * 65 + c] * vi + bias[c];
        if (apply_elu) v = (v > 0.f) ? v : (__expf(v) - 1.0f);
        ov[k] = (_Float16)v;
      }
      *(half8*)(out + (size_t)node * 64 + c0 + o * 8) = ov;
    }
  }
}

extern "C" void kernel_launch(void* const* d_in, const int* in_sizes, int n_in,
                              void* d_out, int out_size, void* d_ws, size_t ws_size,
                              hipStream_t stream) {
  const float* x  = (const float*)d_in[0];
  const int*   src = (const int*)d_in[1];
  const int*   dst = (const int*)d_in[2];
  const float* W0 = (const float*)d_in[3];
  const float* b0 = (const float*)d_in[4];
  const float* W1 = (const float*)d_in[5];
  const float* b1 = (const float*)d_in[6];
  const float* W2 = (const float*)d_in[7];
  const float* b2 = (const float*)d_in[8];
  const float* Wl = (const float*)d_in[9];
  const float* bl = (const float*)d_in[10];

  const int N = in_sizes[0] / 128;
  const int E = in_sizes[1];
  const int NR = (N + RWID - 1) >> RW_SH;
  const int EPC = (((E + NCHUNK - 1) / NCHUNK) + 3) & ~3;
  const int EPCO = (((E + NCO - 1) / NCO) + 3) & ~3;

  int* wsp = (int*)d_ws;
  size_t off = 0;
  auto alloc = [&](size_t n) -> int* {   // 256B-aligned regions
    int* p = wsp + off;
    off += (n + 63) & ~(size_t)63;
    return p;
  };
  float*    invo       = (float*)alloc(N);
  int*      cntA       = alloc((size_t)NR * NCHUNK);
  int*      base_rel   = alloc((size_t)NR * NCHUNK);
  int*      cntR       = alloc(NR);
  int*      rangeStart = alloc((size_t)NR + 1);
  int*      bucket     = alloc(E);
  int*      slab       = alloc((size_t)NCO * N);
  _Float16* hP         = (_Float16*)alloc((size_t)N * 32);  // N x 64 f16
  _Float16* hA         = (_Float16*)alloc((size_t)N * 32);  // N x 64 f16
  _Float16* WT0        = (_Float16*)alloc(64 * 128 / 2);
  _Float16* WT1        = (_Float16*)alloc(64 * 64 / 2);
  _Float16* WT2        = (_Float16*)alloc(64 * 64 / 2);
  _Float16* WTl        = (_Float16*)alloc(64 * 64 / 2);
  (void)ws_size; (void)n_in; (void)out_size;

  const int gN = (N + WG - 1) / WG;
  const int gGemm = (N + 63) / 64;

  // bucket-by-dst build (atomic-free at global scope; stops at bucket stage)
  coarse_hist_kernel<<<NCHUNK, WG, 0, stream>>>(dst, cntA, NR, E, EPC);
  chunkscan_kernel<<<NR, WG, 0, stream>>>(cntA, base_rel, cntR);
  rangescan_kernel<<<1, WG, 0, stream>>>(cntR, rangeStart, NR, E);
  bucket_kernel<<<NCHUNK, WG, 0, stream>>>(src, dst, base_rel, rangeStart, bucket, NR, E, EPC);

  // out-degree via privatized LDS histograms -> invo; weight transposes
  dego_hist_kernel<<<NRO * NCO, WG, 0, stream>>>(src, slab, N, E, EPCO);
  dego_reduce_invo_kernel<<<gN, WG, 0, stream>>>(slab, invo, N);
  wtrans_kernel<<<4, WG, 0, stream>>>(W0, W1, W2, Wl, WT0, WT1, WT2, WTl);

  // layer 0: (x@W0)*invo -> range-agg -> *invi+b0 -> elu
  gemm_conv_mfma<128, false><<<gGemm, 256, 0, stream>>>(x, WT0, invo, hP, N);
  agg_range_kernel<<<NR, WG, 0, stream>>>(hP, bucket, rangeStart, b0, hA, N, 1);
  // layer 1
  gemm_conv_mfma<64, true><<<gGemm, 256, 0, stream>>>(hA, WT1, invo, hP, N);
  agg_range_kernel<<<NR, WG, 0, stream>>>(hP, bucket, rangeStart, b1, hA, N, 1);
  // layer 2 (+ fused elu ahead of the linear head)
  gemm_conv_mfma<64, true><<<gGemm, 256, 0, stream>>>(hA, WT2, invo, hP, N);
  agg_range_kernel<<<NR, WG, 0, stream>>>(hP, bucket, rangeStart, b2, hA, N, 1);
  // head: elu(h2) @ Wl + bl
  gemm_head_mfma<<<gGemm, 256, 0, stream>>>(hA, WTl, bl, (float*)d_out, N);
}

// Round 10
// 291.834 us; speedup vs baseline: 7.4453x; 7.4453x over previous
//
#include <hip/hip_runtime.h>
#include <hip/hip_fp16.h>
#include <cstdint>
#include <cstddef>

// ---------------------------------------------------------------------------
// GCN: 3x GraphConv(norm='both') + linear head, fp32 in/out.
// Round 10 = round 8 revert (round 9's block-per-range agg was latency-bound:
// 782 blocks, 1 gather in flight -> 678us) + agg micro-opts:
//  - 32-edge main loop (4 b128 gathers in flight per lane)
//  - nontemporal rptr/esrc loads + out store (stop evicting the hp gather
//    table from L2; esrc/out are stream-once traffic)
// ---------------------------------------------------------------------------

#define WG 256
static constexpr int NCHUNK = 512;   // edge chunks for dst bucketing
static constexpr int RW_SH  = 7;     // range width = 128 nodes (dst>>7)
static constexpr int RWID   = 1 << RW_SH;
static constexpr int BPRO   = 6256;  // bins per range for dego histogram (25KB)
static constexpr int NRO    = 16;    // dego ranges (16*6256 >= 100000)
static constexpr int NCO    = 40;    // edge chunks for dego histogram

typedef _Float16 half8 __attribute__((ext_vector_type(8)));
typedef _Float16 half2v __attribute__((ext_vector_type(2)));
typedef float f32x4 __attribute__((ext_vector_type(4)));

__device__ __forceinline__ int block_scan_excl(int v, int tid, int* sd, int& total) {
  sd[tid] = v;
  __syncthreads();
  for (int off = 1; off < 256; off <<= 1) {
    int t = (tid >= off) ? sd[tid - off] : 0;
    __syncthreads();
    sd[tid] += t;
    __syncthreads();
  }
  int incl = sd[tid];
  total = sd[255];
  __syncthreads();
  return incl - v;
}

// --- Pass A: per-chunk coarse histogram over dst ranges ---------------------
__global__ __launch_bounds__(WG) void coarse_hist_kernel(const int* __restrict__ dst,
                                                         int* __restrict__ cntA,
                                                         int NR, int E, int EPC) {
  __shared__ int cnt[1024];
  const int c = blockIdx.x, tid = threadIdx.x;
  for (int i = tid; i < NR; i += WG) cnt[i] = 0;
  __syncthreads();
  const int base = c * EPC;
  const int nv4 = EPC >> 2;
  const int4* d4 = (const int4*)(dst + base);
  for (int i = tid; i < nv4; i += WG) {
    const int e = base + (i << 2);
    if (e + 3 < E) {
      const int4 v = d4[i];
      atomicAdd(&cnt[v.x >> RW_SH], 1);
      atomicAdd(&cnt[v.y >> RW_SH], 1);
      atomicAdd(&cnt[v.z >> RW_SH], 1);
      atomicAdd(&cnt[v.w >> RW_SH], 1);
    } else {
      for (int j = 0; j < 4; ++j) {
        const int ee = e + j;
        if (ee < E) atomicAdd(&cnt[dst[ee] >> RW_SH], 1);
      }
    }
  }
  __syncthreads();
  for (int i = tid; i < NR; i += WG) cntA[i * NCHUNK + c] = cnt[i];
}

// --- Pass B1: per-range exclusive scan over the 512 chunks ------------------
__global__ __launch_bounds__(WG) void chunkscan_kernel(const int* __restrict__ cntA,
                                                       int* __restrict__ base_rel,
                                                       int* __restrict__ cntR) {
  __shared__ int sd[256];
  const int r = blockIdx.x, tid = threadIdx.x;
  const int row = r * NCHUNK;
  int t0, t1;
  const int v0 = cntA[row + tid];
  const int e0 = block_scan_excl(v0, tid, sd, t0);
  base_rel[row + tid] = e0;
  const int v1 = cntA[row + 256 + tid];
  const int e1 = block_scan_excl(v1, tid, sd, t1);
  base_rel[row + 256 + tid] = t0 + e1;
  if (tid == 0) cntR[r] = t0 + t1;
}

// --- Pass B2: exclusive scan over up to 1024 ranges -> rangeStart -----------
__global__ __launch_bounds__(WG) void rangescan_kernel(const int* __restrict__ cntR,
                                                       int* __restrict__ rangeStart,
                                                       int* __restrict__ rptr,
                                                       int NR, int N, int E) {
  __shared__ int sd[256];
  const int tid = threadIdx.x;
  int carry = 0;
  for (int base = 0; base < NR; base += 256) {
    const int idx = base + tid;
    const int v = (idx < NR) ? cntR[idx] : 0;
    int tot;
    const int e = block_scan_excl(v, tid, sd, tot);
    if (idx < NR) rangeStart[idx] = carry + e;
    carry += tot;
  }
  if (tid == 0) { rangeStart[NR] = E; rptr[N] = E; }
}

// --- Pass C: bucket scatter with LDS cursors, 4B packed entries -------------
__global__ __launch_bounds__(WG) void bucket_kernel(const int* __restrict__ src,
                                                    const int* __restrict__ dst,
                                                    const int* __restrict__ base_rel,
                                                    const int* __restrict__ rangeStart,
                                                    int* __restrict__ bucket,
                                                    int NR, int E, int EPC) {
  __shared__ int cur[1024];
  const int c = blockIdx.x, tid = threadIdx.x;
  for (int i = tid; i < NR; i += WG) cur[i] = rangeStart[i] + base_rel[i * NCHUNK + c];
  __syncthreads();
  const int base = c * EPC;
  const int nv4 = EPC >> 2;
  const int4* s4 = (const int4*)(src + base);
  const int4* d4 = (const int4*)(dst + base);
  for (int i = tid; i < nv4; i += WG) {
    const int e = base + (i << 2);
    if (e + 3 < E) {
      const int4 sv = s4[i];
      const int4 dv = d4[i];
      int p;
      p = atomicAdd(&cur[dv.x >> RW_SH], 1); bucket[p] = (sv.x << RW_SH) | (dv.x & (RWID - 1));
      p = atomicAdd(&cur[dv.y >> RW_SH], 1); bucket[p] = (sv.y << RW_SH) | (dv.y & (RWID - 1));
      p = atomicAdd(&cur[dv.z >> RW_SH], 1); bucket[p] = (sv.z << RW_SH) | (dv.z & (RWID - 1));
      p = atomicAdd(&cur[dv.w >> RW_SH], 1); bucket[p] = (sv.w << RW_SH) | (dv.w & (RWID - 1));
    } else {
      for (int j = 0; j < 4; ++j) {
        const int ee = e + j;
        if (ee < E) {
          const int s = src[ee], d = dst[ee];
          const int p = atomicAdd(&cur[d >> RW_SH], 1);
          bucket[p] = (s << RW_SH) | (d & (RWID - 1));
        }
      }
    }
  }
}

// --- Pass D: per-range CSR finalize (rptr, degi, esrc) ----------------------
__global__ __launch_bounds__(WG) void csr_kernel(const int* __restrict__ bucket,
                                                 const int* __restrict__ rangeStart,
                                                 int* __restrict__ rptr,
                                                 int* __restrict__ degi,
                                                 int* __restrict__ esrc, int N) {
  __shared__ int hist[RWID], sd[256];
  const int r = blockIdx.x, tid = threadIdx.x;
  const int s0 = rangeStart[r], s1 = rangeStart[r + 1];
  if (tid < RWID) hist[tid] = 0;
  __syncthreads();
  for (int e = s0 + tid; e < s1; e += WG) atomicAdd(&hist[bucket[e] & (RWID - 1)], 1);
  __syncthreads();
  const int v = (tid < RWID) ? hist[tid] : 0;
  int tot;
  const int excl = block_scan_excl(v, tid, sd, tot);
  const int node = (r << RW_SH) + tid;
  if (tid < RWID && node < N) { degi[node] = v; rptr[node] = s0 + excl; }
  if (tid < RWID) hist[tid] = s0 + excl;
  __syncthreads();
  for (int e = s0 + tid; e < s1; e += WG) {
    const int pk = bucket[e];
    const int p = atomicAdd(&hist[pk & (RWID - 1)], 1);
    esrc[p] = pk >> RW_SH;
  }
}

// --- dego: privatized LDS histogram over src, slab + reduce + inv -----------
__global__ __launch_bounds__(WG) void dego_hist_kernel(const int* __restrict__ src,
                                                       int* __restrict__ slab,
                                                       int N, int E, int EPCO) {
  __shared__ int h[BPRO];  // 25 KB
  const int rr = blockIdx.x / NCO, cc = blockIdx.x % NCO;
  const int tid = threadIdx.x;
  for (int i = tid; i < (BPRO >> 2); i += WG) ((int4*)h)[i] = make_int4(0, 0, 0, 0);
  __syncthreads();
  const int lo = rr * BPRO;
  const int base = cc * EPCO;
  const int nv4 = EPCO >> 2;
  const int4* s4 = (const int4*)(src + base);
  for (int i = tid; i < nv4; i += WG) {
    const int e = base + (i << 2);
    if (e + 3 < E) {
      const int4 v = s4[i];
      unsigned b;
      b = (unsigned)(v.x - lo); if (b < (unsigned)BPRO) atomicAdd(&h[b], 1);
      b = (unsigned)(v.y - lo); if (b < (unsigned)BPRO) atomicAdd(&h[b], 1);
      b = (unsigned)(v.z - lo); if (b < (unsigned)BPRO) atomicAdd(&h[b], 1);
      b = (unsigned)(v.w - lo); if (b < (unsigned)BPRO) atomicAdd(&h[b], 1);
    } else {
      for (int j = 0; j < 4; ++j) {
        const int ee = e + j;
        if (ee < E) {
          const unsigned b = (unsigned)(src[ee] - lo);
          if (b < (unsigned)BPRO) atomicAdd(&h[b], 1);
        }
      }
    }
  }
  __syncthreads();
  int* srow = slab + (size_t)cc * N;
  for (int i = tid; i < (BPRO >> 2); i += WG) {
    const int g = lo + (i << 2);
    if (g + 3 < N) {
      ((int4*)(srow + g))[0] = ((const int4*)h)[i];
    } else {
      for (int j = 0; j < 4; ++j)
        if (g + j < N) srow[g + j] = h[(i << 2) + j];
    }
  }
}

__global__ __launch_bounds__(WG) void dego_reduce_inv_kernel(const int* __restrict__ slab,
                                                             const int* __restrict__ degi,
                                                             float* __restrict__ invo,
                                                             float* __restrict__ invi, int N) {
  const int i = blockIdx.x * WG + threadIdx.x;
  if (i >= N) return;
  int s = 0;
#pragma unroll
  for (int c = 0; c < NCO; ++c) s += slab[(size_t)c * N + i];
  if (s < 1) s = 1;
  int dii = degi[i]; if (dii < 1) dii = 1;
  invo[i] = rsqrtf((float)s);
  invi[i] = rsqrtf((float)dii);
}

// --- weight transpose+convert: WT[c][k] = (f16)W[k][c] ----------------------
__global__ __launch_bounds__(WG) void wtrans_kernel(const float* __restrict__ W0,
                                                    const float* __restrict__ W1,
                                                    const float* __restrict__ W2,
                                                    const float* __restrict__ Wl,
                                                    _Float16* __restrict__ T0,
                                                    _Float16* __restrict__ T1,
                                                    _Float16* __restrict__ T2,
                                                    _Float16* __restrict__ Tl) {
  const float* W; _Float16* T; int K;
  switch (blockIdx.x) {
    case 0: W = W0; T = T0; K = 128; break;
    case 1: W = W1; T = T1; K = 64; break;
    case 2: W = W2; T = T2; K = 64; break;
    default: W = Wl; T = Tl; K = 64; break;
  }
  for (int i = threadIdx.x; i < K * 64; i += WG) {
    const int k = i >> 6, c = i & 63;
    T[c * K + k] = (_Float16)W[i];
  }
}

// --- MFMA conv GEMM: hP[r][c] = f16( invo[r] * sum_k in[r][k] W[k][c] ) -----
template <int K, bool F16IN>
__global__ __launch_bounds__(256) void gemm_conv_mfma(const void* __restrict__ inv_,
                                                      const _Float16* __restrict__ WT,
                                                      const float* __restrict__ invo,
                                                      _Float16* __restrict__ hP, int N) {
  const int tid = threadIdx.x;
  const int w = tid >> 6, l = tid & 63;
  const int rowA = blockIdx.x * 64 + w * 16 + (l & 15);
  const int ar = (rowA < N) ? rowA : (N - 1);
  const int g8 = (l >> 4) * 8;

  f32x4 acc[4];
#pragma unroll
  for (int t = 0; t < 4; ++t) acc[t] = (f32x4){0.f, 0.f, 0.f, 0.f};

#pragma unroll
  for (int s = 0; s < K / 32; ++s) {
    const int kb = s * 32 + g8;
    half8 a;
    if constexpr (F16IN) {
      a = *(const half8*)((const _Float16*)inv_ + (size_t)ar * K + kb);
    } else {
      const float* in = (const float*)inv_;
      const float4 f0 = *(const float4*)(in + (size_t)ar * K + kb);
      const float4 f1 = *(const float4*)(in + (size_t)ar * K + kb + 4);
      a[0] = (_Float16)f0.x; a[1] = (_Float16)f0.y; a[2] = (_Float16)f0.z; a[3] = (_Float16)f0.w;
      a[4] = (_Float16)f1.x; a[5] = (_Float16)f1.y; a[6] = (_Float16)f1.z; a[7] = (_Float16)f1.w;
    }
#pragma unroll
    for (int t = 0; t < 4; ++t) {
      const half8 b = *(const half8*)(WT + (size_t)(16 * t + (l & 15)) * K + kb);
      acc[t] = __builtin_amdgcn_mfma_f32_16x16x32_f16(a, b, acc[t], 0, 0, 0);
    }
  }

  const int rbase = blockIdx.x * 64 + w * 16 + (l >> 4) * 4;
#pragma unroll
  for (int r = 0; r < 4; ++r) {
    const int row = rbase + r;
    if (row < N) {
      const float sc = invo[row];
#pragma unroll
      for (int t = 0; t < 4; ++t)
        hP[(size_t)row * 64 + 16 * t + (l & 15)] = (_Float16)(acc[t][r] * sc);
    }
  }
}

// --- MFMA head GEMM (f16 in): out[r][c] = sum_k in[r][k] W[k][c] + bias[c] --
__global__ __launch_bounds__(256) void gemm_head_mfma(const _Float16* __restrict__ in,
                                                      const _Float16* __restrict__ WT,
                                                      const float* __restrict__ bias,
                                                      float* __restrict__ out, int N) {
  constexpr int K = 64;
  const int tid = threadIdx.x;
  const int w = tid >> 6, l = tid & 63;
  const int rowA = blockIdx.x * 64 + w * 16 + (l & 15);
  const int ar = (rowA < N) ? rowA : (N - 1);
  const int g8 = (l >> 4) * 8;

  f32x4 acc[4];
#pragma unroll
  for (int t = 0; t < 4; ++t) acc[t] = (f32x4){0.f, 0.f, 0.f, 0.f};

#pragma unroll
  for (int s = 0; s < K / 32; ++s) {
    const int kb = s * 32 + g8;
    const half8 a = *(const half8*)(in + (size_t)ar * K + kb);
#pragma unroll
    for (int t = 0; t < 4; ++t) {
      const half8 b = *(const half8*)(WT + (size_t)(16 * t + (l & 15)) * K + kb);
      acc[t] = __builtin_amdgcn_mfma_f32_16x16x32_f16(a, b, acc[t], 0, 0, 0);
    }
  }

  const int rbase = blockIdx.x * 64 + w * 16 + (l >> 4) * 4;
#pragma unroll
  for (int r = 0; r < 4; ++r) {
    const int row = rbase + r;
    if (row < N) {
#pragma unroll
      for (int t = 0; t < 4; ++t) {
        const int c = 16 * t + (l & 15);
        out[(size_t)row * 64 + c] = acc[t][r] + bias[c];
      }
    }
  }
}

// --- CSR gather aggregation, 8 lanes per row --------------------------------
// lane = 8*g + f8; gather: hp[esrc[e+g]*64 + f8*8..+8] (b128, 8 edges/wave-ld)
// 32-edge main loop = 4 gathers in flight; fdot2 accumulate; reduce-scatter
// butterfly leaves lane (g,f8) holding feature f8*8+g. rptr/esrc loads and
// the out store are nontemporal (stream-once; keep L2 for the hp table).
__global__ __launch_bounds__(256) void agg_kernel(const _Float16* __restrict__ hp,
                                                  const int* __restrict__ rptr,
                                                  const int* __restrict__ esrc,
                                                  const float* __restrict__ invin,
                                                  const float* __restrict__ bias,
                                                  _Float16* __restrict__ out, int N,
                                                  int apply_elu) {
  const int w = (blockIdx.x * 256 + threadIdx.x) >> 6;  // one wave per dst node
  const int lane = threadIdx.x & 63;
  const int g = lane >> 3;     // edge slot 0..7
  const int f8 = lane & 7;     // feature octet
  if (w >= N) return;
  const int e0 = __builtin_nontemporal_load(rptr + w);
  const int e1 = __builtin_nontemporal_load(rptr + w + 1);
  const int f = f8 * 8 + g;
  const float vi = invin[w];        // hoisted off the epilogue dep chain
  const float bv = bias[f];

  float acc[8];
#pragma unroll
  for (int k = 0; k < 8; ++k) acc[k] = 0.f;

#if __has_builtin(__builtin_amdgcn_fdot2)
  const half2v one2 = {(_Float16)1.0f, (_Float16)1.0f};
#define ACC2(k, x, y) { half2v p; p[0] = (x); p[1] = (y); \
    acc[k] = __builtin_amdgcn_fdot2(p, one2, acc[k], false); }
#else
#define ACC2(k, x, y) acc[k] += (float)(x) + (float)(y);
#endif

  int e = e0;
  for (; e + 32 <= e1; e += 32) {   // 4 gathers in flight
    const int sA = __builtin_nontemporal_load(esrc + e + g);
    const int sB = __builtin_nontemporal_load(esrc + e + 8 + g);
    const int sC = __builtin_nontemporal_load(esrc + e + 16 + g);
    const int sD = __builtin_nontemporal_load(esrc + e + 24 + g);
    const half8 hA8 = *(const half8*)(hp + (size_t)sA * 64 + f8 * 8);
    const half8 hB8 = *(const half8*)(hp + (size_t)sB * 64 + f8 * 8);
    const half8 hC8 = *(const half8*)(hp + (size_t)sC * 64 + f8 * 8);
    const half8 hD8 = *(const half8*)(hp + (size_t)sD * 64 + f8 * 8);
#pragma unroll
    for (int k = 0; k < 8; ++k) { ACC2(k, hA8[k], hB8[k]); ACC2(k, hC8[k], hD8[k]); }
  }
  for (; e + 16 <= e1; e += 16) {   // 2 gathers in flight
    const int sA = __builtin_nontemporal_load(esrc + e + g);
    const int sB = __builtin_nontemporal_load(esrc + e + 8 + g);
    const half8 hA8 = *(const half8*)(hp + (size_t)sA * 64 + f8 * 8);
    const half8 hB8 = *(const half8*)(hp + (size_t)sB * 64 + f8 * 8);
#pragma unroll
    for (int k = 0; k < 8; ++k) ACC2(k, hA8[k], hB8[k]);
  }
  for (; e + 8 <= e1; e += 8) {
    const int s = __builtin_nontemporal_load(esrc + e + g);
    const half8 hv = *(const half8*)(hp + (size_t)s * 64 + f8 * 8);
#pragma unroll
    for (int k = 0; k < 8; ++k) acc[k] += (float)hv[k];
  }
  if (e < e1) {                      // masked tail group
    const int rem = e1 - e;
    int idx = e + g; if (idx > e1 - 1) idx = e1 - 1;
    const int s = __builtin_nontemporal_load(esrc + idx);
    const half8 hv = *(const half8*)(hp + (size_t)s * 64 + f8 * 8);
    const float m = (g < rem) ? 1.f : 0.f;
#pragma unroll
    for (int k = 0; k < 8; ++k) acc[k] = fmaf(m, (float)hv[k], acc[k]);
  }
#undef ACC2

  // reduce-scatter butterfly: each round sends the half the partner keeps.
  const bool gb0 = (g & 1) != 0;
  const float s0 = gb0 ? acc[0] : acc[1];
  const float s1 = gb0 ? acc[2] : acc[3];
  const float s2 = gb0 ? acc[4] : acc[5];
  const float s3 = gb0 ? acc[6] : acc[7];
  const float k0 = (gb0 ? acc[1] : acc[0]) + __shfl_xor(s0, 8);
  const float k1 = (gb0 ? acc[3] : acc[2]) + __shfl_xor(s1, 8);
  const float k2 = (gb0 ? acc[5] : acc[4]) + __shfl_xor(s2, 8);
  const float k3 = (gb0 ? acc[7] : acc[6]) + __shfl_xor(s3, 8);
  const bool gb1 = (g & 2) != 0;
  const float t0 = gb1 ? k0 : k1;
  const float t1 = gb1 ? k2 : k3;
  const float m0 = (gb1 ? k1 : k0) + __shfl_xor(t0, 16);
  const float m1 = (gb1 ? k3 : k2) + __shfl_xor(t1, 16);
  const bool gb2 = (g & 4) != 0;
  const float u0 = gb2 ? m0 : m1;
  float v = (gb2 ? m1 : m0) + __shfl_xor(u0, 32);

  v = v * vi + bv;
  if (apply_elu) v = (v > 0.f) ? v : (__expf(v) - 1.0f);
  __builtin_nontemporal_store((_Float16)v, out + (size_t)w * 64 + f);
}

extern "C" void kernel_launch(void* const* d_in, const int* in_sizes, int n_in,
                              void* d_out, int out_size, void* d_ws, size_t ws_size,
                              hipStream_t stream) {
  const float* x  = (const float*)d_in[0];
  const int*   src = (const int*)d_in[1];
  const int*   dst = (const int*)d_in[2];
  const float* W0 = (const float*)d_in[3];
  const float* b0 = (const float*)d_in[4];
  const float* W1 = (const float*)d_in[5];
  const float* b1 = (const float*)d_in[6];
  const float* W2 = (const float*)d_in[7];
  const float* b2 = (const float*)d_in[8];
  const float* Wl = (const float*)d_in[9];
  const float* bl = (const float*)d_in[10];

  const int N = in_sizes[0] / 128;
  const int E = in_sizes[1];
  const int NR = (N + RWID - 1) >> RW_SH;
  const int EPC = (((E + NCHUNK - 1) / NCHUNK) + 3) & ~3;
  const int EPCO = (((E + NCO - 1) / NCO) + 3) & ~3;

  int* wsp = (int*)d_ws;
  size_t off = 0;
  auto alloc = [&](size_t n) -> int* {   // 256B-aligned regions
    int* p = wsp + off;
    off += (n + 63) & ~(size_t)63;
    return p;
  };
  int*      degi       = alloc(N);
  float*    invo       = (float*)alloc(N);
  float*    invi       = (float*)alloc(N);
  int*      rptr       = alloc((size_t)N + 1);
  int*      esrc       = alloc(E);
  int*      cntA       = alloc((size_t)NR * NCHUNK);
  int*      base_rel   = alloc((size_t)NR * NCHUNK);
  int*      cntR       = alloc(NR);
  int*      rangeStart = alloc((size_t)NR + 1);
  int*      bucket     = alloc(E);
  int*      slab       = alloc((size_t)NCO * N);
  _Float16* hP         = (_Float16*)alloc((size_t)N * 32);  // N x 64 f16
  _Float16* hA         = (_Float16*)alloc((size_t)N * 32);  // N x 64 f16
  _Float16* WT0        = (_Float16*)alloc(64 * 128 / 2);
  _Float16* WT1        = (_Float16*)alloc(64 * 64 / 2);
  _Float16* WT2        = (_Float16*)alloc(64 * 64 / 2);
  _Float16* WTl        = (_Float16*)alloc(64 * 64 / 2);
  (void)ws_size; (void)n_in; (void)out_size;

  const int gN = (N + WG - 1) / WG;
  const int gAgg = (N + 3) / 4;
  const int gGemm = (N + 63) / 64;

  // CSR-by-dst build (atomic-free at global scope)
  coarse_hist_kernel<<<NCHUNK, WG, 0, stream>>>(dst, cntA, NR, E, EPC);
  chunkscan_kernel<<<NR, WG, 0, stream>>>(cntA, base_rel, cntR);
  rangescan_kernel<<<1, WG, 0, stream>>>(cntR, rangeStart, rptr, NR, N, E);
  bucket_kernel<<<NCHUNK, WG, 0, stream>>>(src, dst, base_rel, rangeStart, bucket, NR, E, EPC);
  csr_kernel<<<NR, WG, 0, stream>>>(bucket, rangeStart, rptr, degi, esrc, N);

  // out-degree via privatized LDS histograms + fused inv; weight transposes
  dego_hist_kernel<<<NRO * NCO, WG, 0, stream>>>(src, slab, N, E, EPCO);
  dego_reduce_inv_kernel<<<gN, WG, 0, stream>>>(slab, degi, invo, invi, N);
  wtrans_kernel<<<4, WG, 0, stream>>>(W0, W1, W2, Wl, WT0, WT1, WT2, WTl);

  // layer 0: (x@W0)*invo -> agg -> *invi+b0 -> elu
  gemm_conv_mfma<128, false><<<gGemm, 256, 0, stream>>>(x, WT0, invo, hP, N);
  agg_kernel<<<gAgg, 256, 0, stream>>>(hP, rptr, esrc, invi, b0, hA, N, 1);
  // layer 1
  gemm_conv_mfma<64, true><<<gGemm, 256, 0, stream>>>(hA, WT1, invo, hP, N);
  agg_kernel<<<gAgg, 256, 0, stream>>>(hP, rptr, esrc, invi, b1, hA, N, 1);
  // layer 2 (+ fused elu ahead of the linear head)
  gemm_conv_mfma<64, true><<<gGemm, 256, 0, stream>>>(hA, WT2, invo, hP, N);
  agg_kernel<<<gAgg, 256, 0, stream>>>(hP, rptr, esrc, invi, b2, hA, N, 1);
  // head: elu(h2) @ Wl + bl
  gemm_head_mfma<<<gGemm, 256, 0, stream>>>(hA, WTl, bl, (float*)d_out, N);
}

// Round 11
// 264.515 us; speedup vs baseline: 8.2142x; 1.1033x over previous
//
#include <hip/hip_runtime.h>
#include <hip/hip_fp16.h>
#include <cstdint>
#include <cstddef>

// ---------------------------------------------------------------------------
// GCN: 3x GraphConv(norm='both') + linear head, fp32 in/out.
// Round 11 = round-8 agg restored verbatim (round 10's nt-hints + 32-unroll
// regressed 38.9->47us: VGPR 20->28, de-cached esrc) + dego_hist halved:
//  - two nodes packed per 32-bit LDS counter (1<<((b&1)*16)), BPRO 12512 in
//    the same 25KB -> NRO=8, src re-reads 102MB -> 51MB; slab u16-packed
//    (16MB -> 8MB each way); reduce sums packed words (no carry: deg << 2^16).
// Agg is at its structural floor: ~40G random line-requests/s (round2 fp32 and
// round8 f16 both land there), FETCH 82MB = compulsory per-XCD miss floor.
// ---------------------------------------------------------------------------

#define WG 256
static constexpr int NCHUNK = 512;   // edge chunks for dst bucketing
static constexpr int RW_SH  = 7;     // range width = 128 nodes (dst>>7)
static constexpr int RWID   = 1 << RW_SH;
static constexpr int BPRO   = 12512; // nodes per dego range (packed u16, 25KB)
static constexpr int NRO    = 8;     // dego ranges (8*12512 >= 100000)
static constexpr int NCO    = 40;    // edge chunks for dego histogram

typedef _Float16 half8 __attribute__((ext_vector_type(8)));
typedef _Float16 half2v __attribute__((ext_vector_type(2)));
typedef float f32x4 __attribute__((ext_vector_type(4)));

__device__ __forceinline__ int block_scan_excl(int v, int tid, int* sd, int& total) {
  sd[tid] = v;
  __syncthreads();
  for (int off = 1; off < 256; off <<= 1) {
    int t = (tid >= off) ? sd[tid - off] : 0;
    __syncthreads();
    sd[tid] += t;
    __syncthreads();
  }
  int incl = sd[tid];
  total = sd[255];
  __syncthreads();
  return incl - v;
}

// --- Pass A: per-chunk coarse histogram over dst ranges ---------------------
__global__ __launch_bounds__(WG) void coarse_hist_kernel(const int* __restrict__ dst,
                                                         int* __restrict__ cntA,
                                                         int NR, int E, int EPC) {
  __shared__ int cnt[1024];
  const int c = blockIdx.x, tid = threadIdx.x;
  for (int i = tid; i < NR; i += WG) cnt[i] = 0;
  __syncthreads();
  const int base = c * EPC;
  const int nv4 = EPC >> 2;
  const int4* d4 = (const int4*)(dst + base);
  for (int i = tid; i < nv4; i += WG) {
    const int e = base + (i << 2);
    if (e + 3 < E) {
      const int4 v = d4[i];
      atomicAdd(&cnt[v.x >> RW_SH], 1);
      atomicAdd(&cnt[v.y >> RW_SH], 1);
      atomicAdd(&cnt[v.z >> RW_SH], 1);
      atomicAdd(&cnt[v.w >> RW_SH], 1);
    } else {
      for (int j = 0; j < 4; ++j) {
        const int ee = e + j;
        if (ee < E) atomicAdd(&cnt[dst[ee] >> RW_SH], 1);
      }
    }
  }
  __syncthreads();
  for (int i = tid; i < NR; i += WG) cntA[i * NCHUNK + c] = cnt[i];
}

// --- Pass B1: per-range exclusive scan over the 512 chunks ------------------
__global__ __launch_bounds__(WG) void chunkscan_kernel(const int* __restrict__ cntA,
                                                       int* __restrict__ base_rel,
                                                       int* __restrict__ cntR) {
  __shared__ int sd[256];
  const int r = blockIdx.x, tid = threadIdx.x;
  const int row = r * NCHUNK;
  int t0, t1;
  const int v0 = cntA[row + tid];
  const int e0 = block_scan_excl(v0, tid, sd, t0);
  base_rel[row + tid] = e0;
  const int v1 = cntA[row + 256 + tid];
  const int e1 = block_scan_excl(v1, tid, sd, t1);
  base_rel[row + 256 + tid] = t0 + e1;
  if (tid == 0) cntR[r] = t0 + t1;
}

// --- Pass B2: exclusive scan over up to 1024 ranges -> rangeStart -----------
__global__ __launch_bounds__(WG) void rangescan_kernel(const int* __restrict__ cntR,
                                                       int* __restrict__ rangeStart,
                                                       int* __restrict__ rptr,
                                                       int NR, int N, int E) {
  __shared__ int sd[256];
  const int tid = threadIdx.x;
  int carry = 0;
  for (int base = 0; base < NR; base += 256) {
    const int idx = base + tid;
    const int v = (idx < NR) ? cntR[idx] : 0;
    int tot;
    const int e = block_scan_excl(v, tid, sd, tot);
    if (idx < NR) rangeStart[idx] = carry + e;
    carry += tot;
  }
  if (tid == 0) { rangeStart[NR] = E; rptr[N] = E; }
}

// --- Pass C: bucket scatter with LDS cursors, 4B packed entries -------------
__global__ __launch_bounds__(WG) void bucket_kernel(const int* __restrict__ src,
                                                    const int* __restrict__ dst,
                                                    const int* __restrict__ base_rel,
                                                    const int* __restrict__ rangeStart,
                                                    int* __restrict__ bucket,
                                                    int NR, int E, int EPC) {
  __shared__ int cur[1024];
  const int c = blockIdx.x, tid = threadIdx.x;
  for (int i = tid; i < NR; i += WG) cur[i] = rangeStart[i] + base_rel[i * NCHUNK + c];
  __syncthreads();
  const int base = c * EPC;
  const int nv4 = EPC >> 2;
  const int4* s4 = (const int4*)(src + base);
  const int4* d4 = (const int4*)(dst + base);
  for (int i = tid; i < nv4; i += WG) {
    const int e = base + (i << 2);
    if (e + 3 < E) {
      const int4 sv = s4[i];
      const int4 dv = d4[i];
      int p;
      p = atomicAdd(&cur[dv.x >> RW_SH], 1); bucket[p] = (sv.x << RW_SH) | (dv.x & (RWID - 1));
      p = atomicAdd(&cur[dv.y >> RW_SH], 1); bucket[p] = (sv.y << RW_SH) | (dv.y & (RWID - 1));
      p = atomicAdd(&cur[dv.z >> RW_SH], 1); bucket[p] = (sv.z << RW_SH) | (dv.z & (RWID - 1));
      p = atomicAdd(&cur[dv.w >> RW_SH], 1); bucket[p] = (sv.w << RW_SH) | (dv.w & (RWID - 1));
    } else {
      for (int j = 0; j < 4; ++j) {
        const int ee = e + j;
        if (ee < E) {
          const int s = src[ee], d = dst[ee];
          const int p = atomicAdd(&cur[d >> RW_SH], 1);
          bucket[p] = (s << RW_SH) | (d & (RWID - 1));
        }
      }
    }
  }
}

// --- Pass D: per-range CSR finalize (rptr, degi, esrc) ----------------------
__global__ __launch_bounds__(WG) void csr_kernel(const int* __restrict__ bucket,
                                                 const int* __restrict__ rangeStart,
                                                 int* __restrict__ rptr,
                                                 int* __restrict__ degi,
                                                 int* __restrict__ esrc, int N) {
  __shared__ int hist[RWID], sd[256];
  const int r = blockIdx.x, tid = threadIdx.x;
  const int s0 = rangeStart[r], s1 = rangeStart[r + 1];
  if (tid < RWID) hist[tid] = 0;
  __syncthreads();
  for (int e = s0 + tid; e < s1; e += WG) atomicAdd(&hist[bucket[e] & (RWID - 1)], 1);
  __syncthreads();
  const int v = (tid < RWID) ? hist[tid] : 0;
  int tot;
  const int excl = block_scan_excl(v, tid, sd, tot);
  const int node = (r << RW_SH) + tid;
  if (tid < RWID && node < N) { degi[node] = v; rptr[node] = s0 + excl; }
  if (tid < RWID) hist[tid] = s0 + excl;
  __syncthreads();
  for (int e = s0 + tid; e < s1; e += WG) {
    const int pk = bucket[e];
    const int p = atomicAdd(&hist[pk & (RWID - 1)], 1);
    esrc[p] = pk >> RW_SH;
  }
}

// --- dego: u16-packed privatized LDS histogram over src ---------------------
// Two nodes per 32-bit LDS word: atomicAdd(1 << ((b&1)*16)). Safe: per-node
// total degree << 2^16, so lo-half sums never carry into the hi half.
__global__ __launch_bounds__(WG) void dego_hist_kernel(const int* __restrict__ src,
                                                       int* __restrict__ slab,
                                                       int N, int E, int EPCO) {
  __shared__ int h[BPRO / 2];  // 25 KB, u16 pair per word
  const int rr = blockIdx.x / NCO, cc = blockIdx.x % NCO;
  const int tid = threadIdx.x;
  for (int i = tid; i < (BPRO >> 3); i += WG) ((int4*)h)[i] = make_int4(0, 0, 0, 0);
  __syncthreads();
  const int lo = rr * BPRO;
  const int base = cc * EPCO;
  const int nv4 = EPCO >> 2;
  const int4* s4 = (const int4*)(src + base);
  for (int i = tid; i < nv4; i += WG) {
    const int e = base + (i << 2);
    if (e + 3 < E) {
      const int4 v = s4[i];
      unsigned b;
      b = (unsigned)(v.x - lo); if (b < (unsigned)BPRO) atomicAdd((unsigned*)&h[b >> 1], 1u << ((b & 1) << 4));
      b = (unsigned)(v.y - lo); if (b < (unsigned)BPRO) atomicAdd((unsigned*)&h[b >> 1], 1u << ((b & 1) << 4));
      b = (unsigned)(v.z - lo); if (b < (unsigned)BPRO) atomicAdd((unsigned*)&h[b >> 1], 1u << ((b & 1) << 4));
      b = (unsigned)(v.w - lo); if (b < (unsigned)BPRO) atomicAdd((unsigned*)&h[b >> 1], 1u << ((b & 1) << 4));
    } else {
      for (int j = 0; j < 4; ++j) {
        const int ee = e + j;
        if (ee < E) {
          const unsigned b = (unsigned)(src[ee] - lo);
          if (b < (unsigned)BPRO) atomicAdd((unsigned*)&h[b >> 1], 1u << ((b & 1) << 4));
        }
      }
    }
  }
  __syncthreads();
  const int NW = N >> 1;               // N even
  const int wbase = lo >> 1;           // lo even (BPRO even)
  int* srow = slab + (size_t)cc * NW;
  for (int i = tid; i < (BPRO >> 3); i += WG) {
    const int wg = wbase + (i << 2);
    if (wg + 3 < NW) {
      ((int4*)(srow + wg))[0] = ((const int4*)h)[i];
    } else {
      for (int j = 0; j < 4; ++j)
        if (wg + j < NW) srow[wg + j] = h[(i << 2) + j];
    }
  }
}

__global__ __launch_bounds__(WG) void dego_reduce_inv_kernel(const int* __restrict__ slab,
                                                             const int* __restrict__ degi,
                                                             float* __restrict__ invo,
                                                             float* __restrict__ invi, int N) {
  const int NW = N >> 1;
  const int i = blockIdx.x * WG + threadIdx.x;  // node-pair index
  if (i >= NW) return;
  unsigned s = 0;
#pragma unroll
  for (int c = 0; c < NCO; ++c) s += (unsigned)slab[(size_t)c * NW + i];
  int d0 = (int)(s & 0xffffu); if (d0 < 1) d0 = 1;
  int d1 = (int)(s >> 16);     if (d1 < 1) d1 = 1;
  const int2 dd = *(const int2*)(degi + 2 * i);
  const int i0 = (dd.x < 1) ? 1 : dd.x;
  const int i1 = (dd.y < 1) ? 1 : dd.y;
  *(float2*)(invo + 2 * i) = make_float2(rsqrtf((float)d0), rsqrtf((float)d1));
  *(float2*)(invi + 2 * i) = make_float2(rsqrtf((float)i0), rsqrtf((float)i1));
}

// --- weight transpose+convert: WT[c][k] = (f16)W[k][c] ----------------------
__global__ __launch_bounds__(WG) void wtrans_kernel(const float* __restrict__ W0,
                                                    const float* __restrict__ W1,
                                                    const float* __restrict__ W2,
                                                    const float* __restrict__ Wl,
                                                    _Float16* __restrict__ T0,
                                                    _Float16* __restrict__ T1,
                                                    _Float16* __restrict__ T2,
                                                    _Float16* __restrict__ Tl) {
  const float* W; _Float16* T; int K;
  switch (blockIdx.x) {
    case 0: W = W0; T = T0; K = 128; break;
    case 1: W = W1; T = T1; K = 64; break;
    case 2: W = W2; T = T2; K = 64; break;
    default: W = Wl; T = Tl; K = 64; break;
  }
  for (int i = threadIdx.x; i < K * 64; i += WG) {
    const int k = i >> 6, c = i & 63;
    T[c * K + k] = (_Float16)W[i];
  }
}

// --- MFMA conv GEMM: hP[r][c] = f16( invo[r] * sum_k in[r][k] W[k][c] ) -----
template <int K, bool F16IN>
__global__ __launch_bounds__(256) void gemm_conv_mfma(const void* __restrict__ inv_,
                                                      const _Float16* __restrict__ WT,
                                                      const float* __restrict__ invo,
                                                      _Float16* __restrict__ hP, int N) {
  const int tid = threadIdx.x;
  const int w = tid >> 6, l = tid & 63;
  const int rowA = blockIdx.x * 64 + w * 16 + (l & 15);
  const int ar = (rowA < N) ? rowA : (N - 1);
  const int g8 = (l >> 4) * 8;

  f32x4 acc[4];
#pragma unroll
  for (int t = 0; t < 4; ++t) acc[t] = (f32x4){0.f, 0.f, 0.f, 0.f};

#pragma unroll
  for (int s = 0; s < K / 32; ++s) {
    const int kb = s * 32 + g8;
    half8 a;
    if constexpr (F16IN) {
      a = *(const half8*)((const _Float16*)inv_ + (size_t)ar * K + kb);
    } else {
      const float* in = (const float*)inv_;
      const float4 f0 = *(const float4*)(in + (size_t)ar * K + kb);
      const float4 f1 = *(const float4*)(in + (size_t)ar * K + kb + 4);
      a[0] = (_Float16)f0.x; a[1] = (_Float16)f0.y; a[2] = (_Float16)f0.z; a[3] = (_Float16)f0.w;
      a[4] = (_Float16)f1.x; a[5] = (_Float16)f1.y; a[6] = (_Float16)f1.z; a[7] = (_Float16)f1.w;
    }
#pragma unroll
    for (int t = 0; t < 4; ++t) {
      const half8 b = *(const half8*)(WT + (size_t)(16 * t + (l & 15)) * K + kb);
      acc[t] = __builtin_amdgcn_mfma_f32_16x16x32_f16(a, b, acc[t], 0, 0, 0);
    }
  }

  const int rbase = blockIdx.x * 64 + w * 16 + (l >> 4) * 4;
#pragma unroll
  for (int r = 0; r < 4; ++r) {
    const int row = rbase + r;
    if (row < N) {
      const float sc = invo[row];
#pragma unroll
      for (int t = 0; t < 4; ++t)
        hP[(size_t)row * 64 + 16 * t + (l & 15)] = (_Float16)(acc[t][r] * sc);
    }
  }
}

// --- MFMA head GEMM (f16 in): out[r][c] = sum_k in[r][k] W[k][c] + bias[c] --
__global__ __launch_bounds__(256) void gemm_head_mfma(const _Float16* __restrict__ in,
                                                      const _Float16* __restrict__ WT,
                                                      const float* __restrict__ bias,
                                                      float* __restrict__ out, int N) {
  constexpr int K = 64;
  const int tid = threadIdx.x;
  const int w = tid >> 6, l = tid & 63;
  const int rowA = blockIdx.x * 64 + w * 16 + (l & 15);
  const int ar = (rowA < N) ? rowA : (N - 1);
  const int g8 = (l >> 4) * 8;

  f32x4 acc[4];
#pragma unroll
  for (int t = 0; t < 4; ++t) acc[t] = (f32x4){0.f, 0.f, 0.f, 0.f};

#pragma unroll
  for (int s = 0; s < K / 32; ++s) {
    const int kb = s * 32 + g8;
    const half8 a = *(const half8*)(in + (size_t)ar * K + kb);
#pragma unroll
    for (int t = 0; t < 4; ++t) {
      const half8 b = *(const half8*)(WT + (size_t)(16 * t + (l & 15)) * K + kb);
      acc[t] = __builtin_amdgcn_mfma_f32_16x16x32_f16(a, b, acc[t], 0, 0, 0);
    }
  }

  const int rbase = blockIdx.x * 64 + w * 16 + (l >> 4) * 4;
#pragma unroll
  for (int r = 0; r < 4; ++r) {
    const int row = rbase + r;
    if (row < N) {
#pragma unroll
      for (int t = 0; t < 4; ++t) {
        const int c = 16 * t + (l & 15);
        out[(size_t)row * 64 + c] = acc[t][r] + bias[c];
      }
    }
  }
}

// --- CSR gather aggregation, 8 lanes per row (round-8 version) --------------
// lane = 8*g + f8; gather: hp[esrc[e+g]*64 + f8*8..+8] (b128, 8 edges/wave-ld)
// fdot2 accumulate; reduce-scatter butterfly leaves lane (g,f8) holding
// feature f8*8+g.
__global__ __launch_bounds__(256) void agg_kernel(const _Float16* __restrict__ hp,
                                                  const int* __restrict__ rptr,
                                                  const int* __restrict__ esrc,
                                                  const float* __restrict__ invin,
                                                  const float* __restrict__ bias,
                                                  _Float16* __restrict__ out, int N,
                                                  int apply_elu) {
  const int w = (blockIdx.x * 256 + threadIdx.x) >> 6;  // one wave per dst node
  const int lane = threadIdx.x & 63;
  const int g = lane >> 3;     // edge slot 0..7
  const int f8 = lane & 7;     // feature octet
  if (w >= N) return;
  const int e0 = rptr[w];
  const int e1 = rptr[w + 1];
  const int f = f8 * 8 + g;
  const float vi = invin[w];        // hoisted off the epilogue dep chain
  const float bv = bias[f];

  float acc[8];
#pragma unroll
  for (int k = 0; k < 8; ++k) acc[k] = 0.f;

  int e = e0;
  for (; e + 16 <= e1; e += 16) {   // 2 gathers in flight, fdot2 accumulate
    const int sA = esrc[e + g];
    const int sB = esrc[e + 8 + g];
    const half8 hA8 = *(const half8*)(hp + (size_t)sA * 64 + f8 * 8);
    const half8 hB8 = *(const half8*)(hp + (size_t)sB * 64 + f8 * 8);
#if __has_builtin(__builtin_amdgcn_fdot2)
    const half2v one2 = {(_Float16)1.0f, (_Float16)1.0f};
#pragma unroll
    for (int k = 0; k < 8; ++k) {
      half2v p; p[0] = hA8[k]; p[1] = hB8[k];
      acc[k] = __builtin_amdgcn_fdot2(p, one2, acc[k], false);
    }
#else
#pragma unroll
    for (int k = 0; k < 8; ++k) acc[k] += (float)hA8[k] + (float)hB8[k];
#endif
  }
  for (; e + 8 <= e1; e += 8) {
    const int s = esrc[e + g];
    const half8 hv = *(const half8*)(hp + (size_t)s * 64 + f8 * 8);
#pragma unroll
    for (int k = 0; k < 8; ++k) acc[k] += (float)hv[k];
  }
  if (e < e1) {                      // masked tail group
    const int rem = e1 - e;
    int idx = e + g; if (idx > e1 - 1) idx = e1 - 1;
    const int s = esrc[idx];
    const half8 hv = *(const half8*)(hp + (size_t)s * 64 + f8 * 8);
    const float m = (g < rem) ? 1.f : 0.f;
#pragma unroll
    for (int k = 0; k < 8; ++k) acc[k] = fmaf(m, (float)hv[k], acc[k]);
  }

  // reduce-scatter butterfly: each round sends the half the partner keeps.
  const bool gb0 = (g & 1) != 0;
  const float s0 = gb0 ? acc[0] : acc[1];
  const float s1 = gb0 ? acc[2] : acc[3];
  const float s2 = gb0 ? acc[4] : acc[5];
  const float s3 = gb0 ? acc[6] : acc[7];
  const float k0 = (gb0 ? acc[1] : acc[0]) + __shfl_xor(s0, 8);
  const float k1 = (gb0 ? acc[3] : acc[2]) + __shfl_xor(s1, 8);
  const float k2 = (gb0 ? acc[5] : acc[4]) + __shfl_xor(s2, 8);
  const float k3 = (gb0 ? acc[7] : acc[6]) + __shfl_xor(s3, 8);
  const bool gb1 = (g & 2) != 0;
  const float t0 = gb1 ? k0 : k1;
  const float t1 = gb1 ? k2 : k3;
  const float m0 = (gb1 ? k1 : k0) + __shfl_xor(t0, 16);
  const float m1 = (gb1 ? k3 : k2) + __shfl_xor(t1, 16);
  const bool gb2 = (g & 4) != 0;
  const float u0 = gb2 ? m0 : m1;
  float v = (gb2 ? m1 : m0) + __shfl_xor(u0, 32);

  v = v * vi + bv;
  if (apply_elu) v = (v > 0.f) ? v : (__expf(v) - 1.0f);
  out[(size_t)w * 64 + f] = (_Float16)v;
}

extern "C" void kernel_launch(void* const* d_in, const int* in_sizes, int n_in,
                              void* d_out, int out_size, void* d_ws, size_t ws_size,
                              hipStream_t stream) {
  const float* x  = (const float*)d_in[0];
  const int*   src = (const int*)d_in[1];
  const int*   dst = (const int*)d_in[2];
  const float* W0 = (const float*)d_in[3];
  const float* b0 = (const float*)d_in[4];
  const float* W1 = (const float*)d_in[5];
  const float* b1 = (const float*)d_in[6];
  const float* W2 = (const float*)d_in[7];
  const float* b2 = (const float*)d_in[8];
  const float* Wl = (const float*)d_in[9];
  const float* bl = (const float*)d_in[10];

  const int N = in_sizes[0] / 128;
  const int E = in_sizes[1];
  const int NR = (N + RWID - 1) >> RW_SH;
  const int EPC = (((E + NCHUNK - 1) / NCHUNK) + 3) & ~3;
  const int EPCO = (((E + NCO - 1) / NCO) + 3) & ~3;

  int* wsp = (int*)d_ws;
  size_t off = 0;
  auto alloc = [&](size_t n) -> int* {   // 256B-aligned regions
    int* p = wsp + off;
    off += (n + 63) & ~(size_t)63;
    return p;
  };
  int*      degi       = alloc(N);
  float*    invo       = (float*)alloc(N);
  float*    invi       = (float*)alloc(N);
  int*      rptr       = alloc((size_t)N + 1);
  int*      esrc       = alloc(E);
  int*      cntA       = alloc((size_t)NR * NCHUNK);
  int*      base_rel   = alloc((size_t)NR * NCHUNK);
  int*      cntR       = alloc(NR);
  int*      rangeStart = alloc((size_t)NR + 1);
  int*      bucket     = alloc(E);
  int*      slab       = alloc((size_t)NCO * (N >> 1));  // u16-packed
  _Float16* hP         = (_Float16*)alloc((size_t)N * 32);  // N x 64 f16
  _Float16* hA         = (_Float16*)alloc((size_t)N * 32);  // N x 64 f16
  _Float16* WT0        = (_Float16*)alloc(64 * 128 / 2);
  _Float16* WT1        = (_Float16*)alloc(64 * 64 / 2);
  _Float16* WT2        = (_Float16*)alloc(64 * 64 / 2);
  _Float16* WTl        = (_Float16*)alloc(64 * 64 / 2);
  (void)ws_size; (void)n_in; (void)out_size;

  const int gAgg = (N + 3) / 4;
  const int gGemm = (N + 63) / 64;
  const int gRed = ((N >> 1) + WG - 1) / WG;

  // CSR-by-dst build (atomic-free at global scope)
  coarse_hist_kernel<<<NCHUNK, WG, 0, stream>>>(dst, cntA, NR, E, EPC);
  chunkscan_kernel<<<NR, WG, 0, stream>>>(cntA, base_rel, cntR);
  rangescan_kernel<<<1, WG, 0, stream>>>(cntR, rangeStart, rptr, NR, N, E);
  bucket_kernel<<<NCHUNK, WG, 0, stream>>>(src, dst, base_rel, rangeStart, bucket, NR, E, EPC);
  csr_kernel<<<NR, WG, 0, stream>>>(bucket, rangeStart, rptr, degi, esrc, N);

  // out-degree via u16-packed LDS histograms + fused inv; weight transposes
  dego_hist_kernel<<<NRO * NCO, WG, 0, stream>>>(src, slab, N, E, EPCO);
  dego_reduce_inv_kernel<<<gRed, WG, 0, stream>>>(slab, degi, invo, invi, N);
  wtrans_kernel<<<4, WG, 0, stream>>>(W0, W1, W2, Wl, WT0, WT1, WT2, WTl);

  // layer 0: (x@W0)*invo -> agg -> *invi+b0 -> elu
  gemm_conv_mfma<128, false><<<gGemm, 256, 0, stream>>>(x, WT0, invo, hP, N);
  agg_kernel<<<gAgg, 256, 0, stream>>>(hP, rptr, esrc, invi, b0, hA, N, 1);
  // layer 1
  gemm_conv_mfma<64, true><<<gGemm, 256, 0, stream>>>(hA, WT1, invo, hP, N);
  agg_kernel<<<gAgg, 256, 0, stream>>>(hP, rptr, esrc, invi, b1, hA, N, 1);
  // layer 2 (+ fused elu ahead of the linear head)
  gemm_conv_mfma<64, true><<<gGemm, 256, 0, stream>>>(hA, WT2, invo, hP, N);
  agg_kernel<<<gAgg, 256, 0, stream>>>(hP, rptr, esrc, invi, b2, hA, N, 1);
  // head: elu(h2) @ Wl + bl
  gemm_head_mfma<<<gGemm, 256, 0, stream>>>(hA, WTl, bl, (float*)d_out, N);
}